// Round 1
// baseline (1937.728 us; speedup 1.0000x reference)
//
#include <hip/hip_runtime.h>
#include <math.h>

// ---------------------------------------------------------------------------
// EfficientAttention (dual-stream) — fp32 correctness-first baseline.
// Pipeline (all on `stream`, deterministic, no atomics):
//   6x { dw3x3x3+bias -> pw 256x256 GEMM+bias } -> K/Q/V [N,512,S]
//   softmax_K over S, softmax_Q over 64 head-channels
//   ctx[n,h,64,64] = K.V^T (chunked partials + reduce)
//   att[n,h,64,S]  = ctx^T.Q  -> aggregated (stored in d_out as scratch)
//   rp: dw(512) -> pw 512x512 GEMM -> rep
//   x = rep + concat(rgb,flow); whole-tensor LN via 2-stage double reduction
// Workspace: needs 2.5 * N*512*S floats = ~257 MB.
// ---------------------------------------------------------------------------

constexpr int NN = 4;
constexpr int C1 = 256;
constexpr int C2 = 512;
constexpr int TT = 16;
constexpr int HHD = 28;
constexpr int WWD = 28;
constexpr int SP = TT * HHD * WWD;              // 12544
constexpr long long NB = (long long)NN * C2 * SP; // 25,690,112 floats
constexpr int HEADS = 8;
constexpr int CTX_CHUNKS = 49;                  // SP / 256
constexpr int STATS_BLOCKS = NN * C2;           // 2048
constexpr double TOTAL_ELEMS = (double)NB;

// ---------------- depthwise 3x3x3 conv + bias ------------------------------
// grid: (TT, Cin, NN), block: 256. in/out: [N, Cin, T, 28*28]
__global__ __launch_bounds__(256)
void dw_conv_kernel(const float* __restrict__ in, const float* __restrict__ wgt,
                    const float* __restrict__ bias, float* __restrict__ out, int Cin)
{
    const int t = blockIdx.x, c = blockIdx.y, n = blockIdx.z;
    __shared__ float tile[3][30][30];
    const float* inp = in + ((size_t)(n * Cin + c)) * TT * 784;
    for (int idx = threadIdx.x; idx < 2700; idx += 256) {
        int sl = idx / 900, r = idx - sl * 900;
        int y = r / 30, x = r - y * 30;
        int tt = t + sl - 1, hh = y - 1, ww = x - 1;
        float v = 0.f;
        if (tt >= 0 && tt < TT && hh >= 0 && hh < HHD && ww >= 0 && ww < WWD)
            v = inp[(size_t)tt * 784 + hh * 28 + ww];
        tile[sl][y][x] = v;
    }
    __syncthreads();
    float wreg[27];
#pragma unroll
    for (int i = 0; i < 27; ++i) wreg[i] = wgt[c * 27 + i];
    const float bv = bias[c];
    float* op = out + (((size_t)(n * Cin + c)) * TT + t) * 784;
    for (int idx = threadIdx.x; idx < 784; idx += 256) {
        int hh = idx / 28, ww = idx - hh * 28;
        float acc = bv;
#pragma unroll
        for (int dt = 0; dt < 3; ++dt)
#pragma unroll
            for (int dh = 0; dh < 3; ++dh)
#pragma unroll
                for (int dw = 0; dw < 3; ++dw)
                    acc += wreg[(dt * 3 + dh) * 3 + dw] * tile[dt][hh + dh][ww + dw];
        op[idx] = acc;
    }
}

// ---------------- pointwise conv as tiled fp32 GEMM ------------------------
// out[n, choff+m, s] = sum_k W[m,k] * in[n,k,s] + bias[m]
// grid: (SP/64, Cout/64, NN), block (16,16). 64x64 tile, BK=16, 4x4 microtile.
__global__ __launch_bounds__(256)
void pw_gemm_kernel(const float* __restrict__ W, const float* __restrict__ bias,
                    const float* __restrict__ in, float* __restrict__ out,
                    int Cin, int Cout, int outChanOff, int outCtot)
{
    __shared__ float As[64][17];   // [m][k], padded
    __shared__ float Bs[16][68];   // [k][s], padded
    const int tx = threadIdx.x, ty = threadIdx.y;
    const int tid = ty * 16 + tx;
    const int s0 = blockIdx.x * 64;
    const int m0 = blockIdx.y * 64;
    const int n = blockIdx.z;
    const float* inp = in + (size_t)n * Cin * SP;
    float acc[4][4] = {};
    for (int k0 = 0; k0 < Cin; k0 += 16) {
#pragma unroll
        for (int i = 0; i < 4; ++i) {
            int l = tid + i * 256;
            int mm = l >> 4, kk = l & 15;
            As[mm][kk] = W[(size_t)(m0 + mm) * Cin + k0 + kk];
        }
        {
            int kk = tid >> 4, jj = (tid & 15) * 4;
            const float4 v = *(const float4*)&inp[(size_t)(k0 + kk) * SP + s0 + jj];
            Bs[kk][jj] = v.x; Bs[kk][jj + 1] = v.y; Bs[kk][jj + 2] = v.z; Bs[kk][jj + 3] = v.w;
        }
        __syncthreads();
#pragma unroll
        for (int k = 0; k < 16; ++k) {
            float a[4], b[4];
#pragma unroll
            for (int i = 0; i < 4; ++i) a[i] = As[ty * 4 + i][k];
#pragma unroll
            for (int j = 0; j < 4; ++j) b[j] = Bs[k][tx * 4 + j];
#pragma unroll
            for (int i = 0; i < 4; ++i)
#pragma unroll
                for (int j = 0; j < 4; ++j)
                    acc[i][j] += a[i] * b[j];
        }
        __syncthreads();
    }
    float* op = out + ((size_t)n * outCtot + outChanOff) * SP;
#pragma unroll
    for (int i = 0; i < 4; ++i) {
        int m = m0 + ty * 4 + i;
        float bv = bias[m];
        float4 v;
        v.x = acc[i][0] + bv; v.y = acc[i][1] + bv;
        v.z = acc[i][2] + bv; v.w = acc[i][3] + bv;
        *(float4*)&op[(size_t)m * SP + s0 + tx * 4] = v;
    }
}

// ---------------- softmax over S (rows of [N*512, S]) ----------------------
__global__ __launch_bounds__(256)
void softmax_rows_kernel(float* __restrict__ data)
{
    float* p = data + (size_t)blockIdx.x * SP;
    __shared__ float sm[4];
    __shared__ float bc;
    const int tid = threadIdx.x, wv = tid >> 6, ln = tid & 63;
    float m = -1e30f;
    for (int i = tid; i < SP; i += 256) m = fmaxf(m, p[i]);
    for (int o = 32; o; o >>= 1) m = fmaxf(m, __shfl_down(m, o, 64));
    if (ln == 0) sm[wv] = m;
    __syncthreads();
    if (tid == 0) bc = fmaxf(fmaxf(sm[0], sm[1]), fmaxf(sm[2], sm[3]));
    __syncthreads();
    m = bc;
    float sum = 0.f;
    for (int i = tid; i < SP; i += 256) { float e = __expf(p[i] - m); p[i] = e; sum += e; }
    for (int o = 32; o; o >>= 1) sum += __shfl_down(sum, o, 64);
    __syncthreads();
    if (ln == 0) sm[wv] = sum;
    __syncthreads();
    if (tid == 0) bc = sm[0] + sm[1] + sm[2] + sm[3];
    __syncthreads();
    const float inv = 1.f / bc;
    for (int i = tid; i < SP; i += 256) p[i] *= inv;
}

// ---------------- softmax over 64 head-channels (Q) ------------------------
// grid: (SP/256, N*HEADS), block 256. One thread per spatial position.
__global__ __launch_bounds__(256)
void softmax_q_kernel(float* __restrict__ data)
{
    const int s = blockIdx.x * 256 + threadIdx.x;
    const int nh = blockIdx.y;
    const int n = nh >> 3, h = nh & 7;
    float* p = data + ((size_t)n * C2 + h * 64) * SP + s;
    float v[64];
    float m = -1e30f;
#pragma unroll
    for (int c = 0; c < 64; ++c) { v[c] = p[(size_t)c * SP]; m = fmaxf(m, v[c]); }
    float sum = 0.f;
#pragma unroll
    for (int c = 0; c < 64; ++c) { v[c] = __expf(v[c] - m); sum += v[c]; }
    const float inv = 1.f / sum;
#pragma unroll
    for (int c = 0; c < 64; ++c) p[(size_t)c * SP] = v[c] * inv;
}

// ---------------- ctx = K . V^T (chunked partials) -------------------------
// grid: (CTX_CHUNKS, N*HEADS), block 256. Each block: 64x64 over 256 s-positions.
__global__ __launch_bounds__(256)
void ctx_partial_kernel(const float* __restrict__ Kbuf, const float* __restrict__ Vbuf,
                        float* __restrict__ part)
{
    const int chunk = blockIdx.x, nh = blockIdx.y;
    const int sBeg = chunk * 256;
    const float* Kp = Kbuf + (size_t)nh * 64 * SP;
    const float* Vp = Vbuf + (size_t)nh * 64 * SP;
    __shared__ float Ks[64][33], Vs[64][33];
    const int tid = threadIdx.x;
    const int kk = (tid >> 4) * 4, vv = (tid & 15) * 4;
    float acc[4][4] = {};
    for (int st = 0; st < 256; st += 32) {
#pragma unroll
        for (int i = 0; i < 2; ++i) {
            int l = tid + i * 256;          // quad index, 512 quads = 2 matrices rows
            int r = l >> 3, cq = (l & 7) * 4;
            float4 a = *(const float4*)&Kp[(size_t)r * SP + sBeg + st + cq];
            Ks[r][cq] = a.x; Ks[r][cq + 1] = a.y; Ks[r][cq + 2] = a.z; Ks[r][cq + 3] = a.w;
            float4 b = *(const float4*)&Vp[(size_t)r * SP + sBeg + st + cq];
            Vs[r][cq] = b.x; Vs[r][cq + 1] = b.y; Vs[r][cq + 2] = b.z; Vs[r][cq + 3] = b.w;
        }
        __syncthreads();
#pragma unroll 8
        for (int s = 0; s < 32; ++s) {
            float a[4], b[4];
#pragma unroll
            for (int i = 0; i < 4; ++i) a[i] = Ks[kk + i][s];
#pragma unroll
            for (int j = 0; j < 4; ++j) b[j] = Vs[vv + j][s];
#pragma unroll
            for (int i = 0; i < 4; ++i)
#pragma unroll
                for (int j = 0; j < 4; ++j)
                    acc[i][j] += a[i] * b[j];
        }
        __syncthreads();
    }
    float* op = part + ((size_t)nh * CTX_CHUNKS + chunk) * 4096;
#pragma unroll
    for (int i = 0; i < 4; ++i)
#pragma unroll
        for (int j = 0; j < 4; ++j)
            op[(kk + i) * 64 + vv + j] = acc[i][j];
}

__global__ __launch_bounds__(256)
void ctx_reduce_kernel(const float* __restrict__ part, float* __restrict__ ctx)
{
    const int nh = blockIdx.x;
    for (int e = threadIdx.x; e < 4096; e += 256) {
        float s = 0.f;
        for (int c = 0; c < CTX_CHUNKS; ++c)
            s += part[((size_t)nh * CTX_CHUNKS + c) * 4096 + e];
        ctx[(size_t)nh * 4096 + e] = s;
    }
}

// ---------------- att[v,s] = sum_k ctx[k,v] * Q[k,s] -----------------------
// grid: (SP/64, N*HEADS), block (16,16).
__global__ __launch_bounds__(256)
void att_kernel(const float* __restrict__ ctx, const float* __restrict__ Qbuf,
                float* __restrict__ out)
{
    const int nh = blockIdx.y;
    const int s0 = blockIdx.x * 64;
    const float* cp = ctx + (size_t)nh * 4096;
    const float* Qp = Qbuf + (size_t)nh * 64 * SP;
    float* op = out + (size_t)nh * 64 * SP;
    __shared__ float Cs[64][65];   // [k][v]
    __shared__ float Bs[64][68];   // [k][s]
    const int tx = threadIdx.x, ty = threadIdx.y;
    const int tid = ty * 16 + tx;
#pragma unroll
    for (int i = 0; i < 4; ++i) {
        int q = tid + i * 256;               // 1024 quads = 4096 floats
        int k = q >> 4, v4 = (q & 15) * 4;
        float4 a = *(const float4*)&cp[k * 64 + v4];
        Cs[k][v4] = a.x; Cs[k][v4 + 1] = a.y; Cs[k][v4 + 2] = a.z; Cs[k][v4 + 3] = a.w;
        float4 b = *(const float4*)&Qp[(size_t)k * SP + s0 + v4];
        Bs[k][v4] = b.x; Bs[k][v4 + 1] = b.y; Bs[k][v4 + 2] = b.z; Bs[k][v4 + 3] = b.w;
    }
    __syncthreads();
    float acc[4][4] = {};
    const int v0 = ty * 4, j0 = tx * 4;
#pragma unroll 8
    for (int k = 0; k < 64; ++k) {
        float a[4], b[4];
#pragma unroll
        for (int i = 0; i < 4; ++i) a[i] = Cs[k][v0 + i];
#pragma unroll
        for (int j = 0; j < 4; ++j) b[j] = Bs[k][j0 + j];
#pragma unroll
        for (int i = 0; i < 4; ++i)
#pragma unroll
            for (int j = 0; j < 4; ++j)
                acc[i][j] += a[i] * b[j];
    }
#pragma unroll
    for (int i = 0; i < 4; ++i) {
        float4 v;
        v.x = acc[i][0]; v.y = acc[i][1]; v.z = acc[i][2]; v.w = acc[i][3];
        *(float4*)&op[(size_t)(v0 + i) * SP + s0 + j0] = v;
    }
}

// ---------------- x = rep + fused ; per-block partial sums -----------------
// grid: N*512 blocks (one per (n,channel) row), block 256.
__global__ __launch_bounds__(256)
void add_stats_kernel(const float* __restrict__ rep, const float* __restrict__ rgb,
                      const float* __restrict__ flow, float* __restrict__ xout,
                      double* __restrict__ partials)
{
    const int nc = blockIdx.x;
    const int n = nc >> 9, c = nc & 511;
    const float* f = (c < 256) ? rgb + ((size_t)n * 256 + c) * SP
                               : flow + ((size_t)n * 256 + (c - 256)) * SP;
    const float* r = rep + (size_t)nc * SP;
    float* xo = xout + (size_t)nc * SP;
    double ls = 0.0, lss = 0.0;
    for (int i = threadIdx.x; i < SP; i += 256) {
        float x = r[i] + f[i];
        xo[i] = x;
        ls += (double)x;
        lss += (double)x * (double)x;
    }
    __shared__ double s1[256], s2[256];
    const int tid = threadIdx.x;
    s1[tid] = ls; s2[tid] = lss;
    __syncthreads();
    for (int s = 128; s > 0; s >>= 1) {
        if (tid < s) { s1[tid] += s1[tid + s]; s2[tid] += s2[tid + s]; }
        __syncthreads();
    }
    if (tid == 0) {
        partials[2 * nc] = s1[0];
        partials[2 * nc + 1] = s2[0];
    }
}

__global__ __launch_bounds__(256)
void stats_final_kernel(const double* __restrict__ partials, float* __restrict__ mv)
{
    double ls = 0.0, lss = 0.0;
    for (int i = threadIdx.x; i < STATS_BLOCKS; i += 256) {
        ls += partials[2 * i];
        lss += partials[2 * i + 1];
    }
    __shared__ double s1[256], s2[256];
    const int tid = threadIdx.x;
    s1[tid] = ls; s2[tid] = lss;
    __syncthreads();
    for (int s = 128; s > 0; s >>= 1) {
        if (tid < s) { s1[tid] += s1[tid + s]; s2[tid] += s2[tid + s]; }
        __syncthreads();
    }
    if (tid == 0) {
        double mean = s1[0] / TOTAL_ELEMS;
        double var = s2[0] / TOTAL_ELEMS - mean * mean;
        mv[0] = (float)mean;
        mv[1] = (float)(1.0 / sqrt(var + 1e-5));
    }
}

__global__ __launch_bounds__(256)
void normalize_kernel(float* __restrict__ x, const float* __restrict__ mv)
{
    const float mean = mv[0], inv = mv[1];
    float* p = x + (size_t)blockIdx.x * SP;
    for (int i = threadIdx.x; i < SP; i += 256)
        p[i] = (p[i] - mean) * inv;
}

// ---------------------------------------------------------------------------
extern "C" void kernel_launch(void* const* d_in, const int* in_sizes, int n_in,
                              void* d_out, int out_size, void* d_ws, size_t ws_size,
                              hipStream_t stream)
{
    (void)in_sizes; (void)n_in; (void)out_size; (void)ws_size;
    const float* rgb = (const float*)d_in[0];
    const float* flow = (const float*)d_in[1];
    float* ws = (float*)d_ws;
    float* bufK = ws;                        // [N,512,S]
    float* bufQ = ws + NB;                   // [N,512,S]
    float* bufT = ws + 2 * NB;               // dw temp [N,256,S] (projections)
    float* bufV = (float*)d_out;             // [N,512,S] — V, then aggregated
    // ctx region aliases bufT (temporally disjoint)
    float* ctxPart = bufT;                                   // 32*49*4096 floats
    float* ctxBuf = bufT + (size_t)32 * CTX_CHUNKS * 4096;   // 32*4096 floats
    double* partials = (double*)(ctxBuf + 32 * 4096);        // 2*2048 doubles
    float* mv = (float*)(partials + 2 * STATS_BLOCKS);       // 2 floats

    const int wb[6] = {2, 6, 10, 14, 18, 22};
    const float* src[6] = {rgb, rgb, rgb, flow, flow, flow};
    float* dst[6] = {bufK, bufQ, bufV, bufK, bufQ, bufV};
    const int choff[6] = {0, 0, 0, 256, 256, 256};

    for (int p = 0; p < 6; ++p) {
        dw_conv_kernel<<<dim3(TT, C1, NN), 256, 0, stream>>>(
            src[p], (const float*)d_in[wb[p]], (const float*)d_in[wb[p] + 1], bufT, C1);
        pw_gemm_kernel<<<dim3(SP / 64, C1 / 64, NN), dim3(16, 16), 0, stream>>>(
            (const float*)d_in[wb[p] + 2], (const float*)d_in[wb[p] + 3], bufT, dst[p],
            C1, C1, choff[p], C2);
    }

    softmax_rows_kernel<<<NN * C2, 256, 0, stream>>>(bufK);
    softmax_q_kernel<<<dim3(SP / 256, NN * HEADS), 256, 0, stream>>>(bufQ);

    ctx_partial_kernel<<<dim3(CTX_CHUNKS, NN * HEADS), 256, 0, stream>>>(bufK, bufV, ctxPart);
    ctx_reduce_kernel<<<NN * HEADS, 256, 0, stream>>>(ctxPart, ctxBuf);
    att_kernel<<<dim3(SP / 64, NN * HEADS), dim3(16, 16), 0, stream>>>(ctxBuf, bufQ, bufV);

    // reprojection: dw(512ch) on aggregated -> bufK ; pw 512x512 -> bufQ (rep)
    dw_conv_kernel<<<dim3(TT, C2, NN), 256, 0, stream>>>(
        bufV, (const float*)d_in[26], (const float*)d_in[27], bufK, C2);
    pw_gemm_kernel<<<dim3(SP / 64, C2 / 64, NN), dim3(16, 16), 0, stream>>>(
        (const float*)d_in[28], (const float*)d_in[29], bufK, bufQ, C2, C2, 0, C2);

    // x = rep + fused ; LN over whole tensor
    add_stats_kernel<<<STATS_BLOCKS, 256, 0, stream>>>(bufQ, rgb, flow, (float*)d_out, partials);
    stats_final_kernel<<<1, 256, 0, stream>>>(partials, mv);
    normalize_kernel<<<STATS_BLOCKS, 256, 0, stream>>>((float*)d_out, mv);
}

// Round 2
// 1235.535 us; speedup vs baseline: 1.5683x; 1.5683x over previous
//
#include <hip/hip_runtime.h>
#include <math.h>

// ---------------------------------------------------------------------------
// EfficientAttention (dual-stream) — round 2: bf16 MFMA pointwise GEMMs.
//   dw conv (fp32 in -> bf16 out [C][S]) -> transpose ([C][S] -> [S][C] bf16)
//   -> MFMA GEMM D[m][s] = W[m][k]*actT[s][k] (both operands K-contiguous),
//      128x128 tile, BK=64, global_load_lds w/ XOR-swizzled source+read.
//   Attention math (softmaxes, ctx, att) stays fp32. Whole-tensor LN in double.
// Q stored channels-major [c][n][s] so dw-temp aliases its dead half.
// ---------------------------------------------------------------------------

constexpr int NN = 4;
constexpr int C1 = 256;
constexpr int C2 = 512;
constexpr int TT = 16;
constexpr int HHD = 28;
constexpr int WWD = 28;
constexpr int SP = TT * HHD * WWD;                // 12544
constexpr long long NB = (long long)NN * C2 * SP; // 25,690,112 floats
constexpr int HEADS = 8;
constexpr int CTX_CHUNKS = 49;                    // SP / 256
constexpr int STATS_BLOCKS = NN * C2;             // 2048
constexpr double TOTAL_ELEMS = (double)NB;

typedef __attribute__((ext_vector_type(8))) short bf16x8;
typedef __attribute__((ext_vector_type(4))) float f32x4;

__device__ __forceinline__ short f2bf(float f)
{
    unsigned u = __float_as_uint(f);
    unsigned r = u + 0x7FFFu + ((u >> 16) & 1u);
    return (short)(r >> 16);
}

__device__ __forceinline__ void gload16(const short* g, short* l)
{
    __builtin_amdgcn_global_load_lds(
        (const __attribute__((address_space(1))) unsigned int*)g,
        (__attribute__((address_space(3))) unsigned int*)l,
        16, 0, 0);
}

// ---------------- fp32 -> bf16 weight conversion ---------------------------
__global__ __launch_bounds__(256)
void cvt_kernel(const float* __restrict__ in, short* __restrict__ out, int n)
{
    int i = blockIdx.x * 1024 + threadIdx.x;
#pragma unroll
    for (int k = 0; k < 4; ++k, i += 256)
        if (i < n) out[i] = f2bf(in[i]);
}

// ---------------- depthwise 3x3x3 conv + bias -> bf16 ----------------------
// grid: (TT, Cin, NN), block: 256. in: [N,Cin,T,784] fp32; out: same, bf16.
__global__ __launch_bounds__(256)
void dw_conv_kernel(const float* __restrict__ in, const float* __restrict__ wgt,
                    const float* __restrict__ bias, short* __restrict__ out, int Cin)
{
    const int t = blockIdx.x, c = blockIdx.y, n = blockIdx.z;
    __shared__ float tile[3][30][30];
    const float* inp = in + ((size_t)(n * Cin + c)) * TT * 784;
    for (int idx = threadIdx.x; idx < 2700; idx += 256) {
        int sl = idx / 900, r = idx - sl * 900;
        int y = r / 30, x = r - y * 30;
        int tt = t + sl - 1, hh = y - 1, ww = x - 1;
        float v = 0.f;
        if (tt >= 0 && tt < TT && hh >= 0 && hh < HHD && ww >= 0 && ww < WWD)
            v = inp[(size_t)tt * 784 + hh * 28 + ww];
        tile[sl][y][x] = v;
    }
    __syncthreads();
    float wreg[27];
#pragma unroll
    for (int i = 0; i < 27; ++i) wreg[i] = wgt[c * 27 + i];
    const float bv = bias[c];
    short* op = out + (((size_t)(n * Cin + c)) * TT + t) * 784;
    for (int idx = threadIdx.x; idx < 784; idx += 256) {
        int hh = idx / 28, ww = idx - hh * 28;
        float acc = bv;
#pragma unroll
        for (int dt = 0; dt < 3; ++dt)
#pragma unroll
            for (int dh = 0; dh < 3; ++dh)
#pragma unroll
                for (int dw = 0; dw < 3; ++dw)
                    acc += wreg[(dt * 3 + dh) * 3 + dw] * tile[dt][hh + dh][ww + dw];
        op[idx] = f2bf(acc);
    }
}

// ---------------- bf16 transpose [C][S] -> [S][C] --------------------------
// grid: (SP/64, C/64, NN), block 256.
__global__ __launch_bounds__(256)
void transpose_kernel(const short* __restrict__ in, short* __restrict__ outT, int C)
{
    __shared__ short t[64][72];
    const int s0 = blockIdx.x * 64, c0 = blockIdx.y * 64, n = blockIdx.z;
    const short* ip = in + ((size_t)n * C + c0) * SP + s0;
    short* op = outT + ((size_t)n * SP + s0) * C + c0;
    const int tid = threadIdx.x;
    const int r = tid >> 3, q = (tid & 7) << 3;
#pragma unroll
    for (int p = 0; p < 2; ++p) {
        int c = r + p * 32;
        *(bf16x8*)&t[c][q] = *(const bf16x8*)(ip + (size_t)c * SP + q);
    }
    __syncthreads();
#pragma unroll
    for (int p = 0; p < 2; ++p) {
        int s = r + p * 32;
        bf16x8 v;
#pragma unroll
        for (int j = 0; j < 8; ++j) v[j] = t[q + j][s];
        *(bf16x8*)(op + (size_t)s * C + q) = v;
    }
}

// ---------------- pointwise conv: bf16 MFMA GEMM ---------------------------
// D[m][s] = sum_k W[m][k]*actT[s][k] + bias[m]
// Wb: [Cout][Cin] bf16; actT: [N][S][Cin] bf16.
// out addr = n*nStride + (chOff+m)*cStride + s  (fp32).
// grid: (SP/128, Cout/128, NN), block 256 (4 waves, each 64x64 output).
__global__ __launch_bounds__(256)
void pw_mfma_kernel(const short* __restrict__ Wb, const float* __restrict__ bias,
                    const short* __restrict__ actT, float* __restrict__ out,
                    int Cin, size_t nStride, size_t cStride, int chOff)
{
    __shared__ short lA[128 * 64];
    __shared__ short lB[128 * 64];
    const int tid = threadIdx.x;
    const int w = tid >> 6, lane = tid & 63;
    const int s0 = blockIdx.x * 128;
    const int m0 = blockIdx.y * 128;
    const int n = blockIdx.z;
    const short* aSrc = Wb + (size_t)m0 * Cin;
    const short* bSrc = actT + ((size_t)n * SP + s0) * Cin;
    f32x4 acc[4][4];
#pragma unroll
    for (int i = 0; i < 4; ++i)
#pragma unroll
        for (int j = 0; j < 4; ++j)
            acc[i][j] = (f32x4){0.f, 0.f, 0.f, 0.f};
    const int lrow = lane >> 3, lslot = lane & 7;
    const int wr = w >> 1, wc = w & 1;

    for (int kt = 0; kt < Cin; kt += 64) {
        // stage 128x64 bf16 tiles of W and actT; LDS linear dest, source
        // pre-swizzled with the same involution used on the read side.
#pragma unroll
        for (int c = 0; c < 4; ++c) {
            const int chunk = w * 4 + c;
            const int row = chunk * 8 + lrow;
            const int ss = lslot ^ (row & 7);
            gload16(aSrc + (size_t)row * Cin + kt + ss * 8, &lA[chunk * 512]);
            gload16(bSrc + (size_t)row * Cin + kt + ss * 8, &lB[chunk * 512]);
        }
        __syncthreads();
#pragma unroll
        for (int kf = 0; kf < 2; ++kf) {
            bf16x8 af[4], bfr[4];
            const int kb = kf * 4 + (lane >> 4);
#pragma unroll
            for (int i = 0; i < 4; ++i) {
                const int row = wr * 64 + i * 16 + (lane & 15);
                af[i] = *(const bf16x8*)&lA[row * 64 + ((kb ^ (row & 7)) << 3)];
            }
#pragma unroll
            for (int j = 0; j < 4; ++j) {
                const int row = wc * 64 + j * 16 + (lane & 15);
                bfr[j] = *(const bf16x8*)&lB[row * 64 + ((kb ^ (row & 7)) << 3)];
            }
#pragma unroll
            for (int i = 0; i < 4; ++i)
#pragma unroll
                for (int j = 0; j < 4; ++j)
                    acc[i][j] = __builtin_amdgcn_mfma_f32_16x16x32_bf16(
                        af[i], bfr[j], acc[i][j], 0, 0, 0);
        }
        __syncthreads();
    }

    // epilogue: D row=(lane>>4)*4+reg (m), col=lane&15 (s); coalesced stores.
    float* op = out + (size_t)n * nStride + (size_t)chOff * cStride;
#pragma unroll
    for (int i = 0; i < 4; ++i) {
        const int mBase = m0 + wr * 64 + i * 16 + (lane >> 4) * 4;
#pragma unroll
        for (int j = 0; j < 4; ++j) {
            const int s = s0 + wc * 64 + j * 16 + (lane & 15);
#pragma unroll
            for (int r = 0; r < 4; ++r) {
                const int m = mBase + r;
                op[(size_t)m * cStride + s] = acc[i][j][r] + bias[m];
            }
        }
    }
}

// ---------------- softmax over S (rows of [*, S]) --------------------------
__global__ __launch_bounds__(256)
void softmax_rows_kernel(float* __restrict__ data)
{
    float* p = data + (size_t)blockIdx.x * SP;
    __shared__ float sm[4];
    __shared__ float bc;
    const int tid = threadIdx.x, wv = tid >> 6, ln = tid & 63;
    float m = -1e30f;
    for (int i = tid; i < SP; i += 256) m = fmaxf(m, p[i]);
    for (int o = 32; o; o >>= 1) m = fmaxf(m, __shfl_down(m, o, 64));
    if (ln == 0) sm[wv] = m;
    __syncthreads();
    if (tid == 0) bc = fmaxf(fmaxf(sm[0], sm[1]), fmaxf(sm[2], sm[3]));
    __syncthreads();
    m = bc;
    float sum = 0.f;
    for (int i = tid; i < SP; i += 256) { float e = __expf(p[i] - m); p[i] = e; sum += e; }
    for (int o = 32; o; o >>= 1) sum += __shfl_down(sum, o, 64);
    __syncthreads();
    if (ln == 0) sm[wv] = sum;
    __syncthreads();
    if (tid == 0) bc = sm[0] + sm[1] + sm[2] + sm[3];
    __syncthreads();
    const float inv = 1.f / bc;
    for (int i = tid; i < SP; i += 256) p[i] *= inv;
}

// ---------------- softmax over 64 head-channels (Q, layout [c][n][s]) ------
__global__ __launch_bounds__(256)
void softmax_q_kernel(float* __restrict__ data)
{
    const int s = blockIdx.x * 256 + threadIdx.x;
    const int nh = blockIdx.y;
    const int n = nh >> 3, h = nh & 7;
    const size_t cs = (size_t)NN * SP;
    float* p = data + (size_t)(h * 64) * cs + (size_t)n * SP + s;
    float v[64];
    float m = -1e30f;
#pragma unroll
    for (int c = 0; c < 64; ++c) { v[c] = p[c * cs]; m = fmaxf(m, v[c]); }
    float sum = 0.f;
#pragma unroll
    for (int c = 0; c < 64; ++c) { v[c] = __expf(v[c] - m); sum += v[c]; }
    const float inv = 1.f / sum;
#pragma unroll
    for (int c = 0; c < 64; ++c) p[c * cs] = v[c] * inv;
}

// ---------------- ctx = K . V^T (chunked partials) -------------------------
__global__ __launch_bounds__(256)
void ctx_partial_kernel(const float* __restrict__ Kbuf, const float* __restrict__ Vbuf,
                        float* __restrict__ part)
{
    const int chunk = blockIdx.x, nh = blockIdx.y;
    const int sBeg = chunk * 256;
    const float* Kp = Kbuf + (size_t)nh * 64 * SP;
    const float* Vp = Vbuf + (size_t)nh * 64 * SP;
    __shared__ float Ks[64][33], Vs[64][33];
    const int tid = threadIdx.x;
    const int kk = (tid >> 4) * 4, vv = (tid & 15) * 4;
    float acc[4][4] = {};
    for (int st = 0; st < 256; st += 32) {
#pragma unroll
        for (int i = 0; i < 2; ++i) {
            int l = tid + i * 256;
            int r = l >> 3, cq = (l & 7) * 4;
            float4 a = *(const float4*)&Kp[(size_t)r * SP + sBeg + st + cq];
            Ks[r][cq] = a.x; Ks[r][cq + 1] = a.y; Ks[r][cq + 2] = a.z; Ks[r][cq + 3] = a.w;
            float4 b = *(const float4*)&Vp[(size_t)r * SP + sBeg + st + cq];
            Vs[r][cq] = b.x; Vs[r][cq + 1] = b.y; Vs[r][cq + 2] = b.z; Vs[r][cq + 3] = b.w;
        }
        __syncthreads();
#pragma unroll 8
        for (int s = 0; s < 32; ++s) {
            float a[4], b[4];
#pragma unroll
            for (int i = 0; i < 4; ++i) a[i] = Ks[kk + i][s];
#pragma unroll
            for (int j = 0; j < 4; ++j) b[j] = Vs[vv + j][s];
#pragma unroll
            for (int i = 0; i < 4; ++i)
#pragma unroll
                for (int j = 0; j < 4; ++j)
                    acc[i][j] += a[i] * b[j];
        }
        __syncthreads();
    }
    float* op = part + ((size_t)nh * CTX_CHUNKS + chunk) * 4096;
#pragma unroll
    for (int i = 0; i < 4; ++i)
#pragma unroll
        for (int j = 0; j < 4; ++j)
            op[(kk + i) * 64 + vv + j] = acc[i][j];
}

__global__ __launch_bounds__(256)
void ctx_reduce_kernel(const float* __restrict__ part, float* __restrict__ ctx)
{
    const int nh = blockIdx.x;
    for (int e = threadIdx.x; e < 4096; e += 256) {
        float s = 0.f;
        for (int c = 0; c < CTX_CHUNKS; ++c)
            s += part[((size_t)nh * CTX_CHUNKS + c) * 4096 + e];
        ctx[(size_t)nh * 4096 + e] = s;
    }
}

// ---------------- att[v,s] = sum_k ctx[k,v] * Q[k,s] (Q layout [c][n][s]) --
__global__ __launch_bounds__(256)
void att_kernel(const float* __restrict__ ctx, const float* __restrict__ Qbuf,
                float* __restrict__ out)
{
    const int nh = blockIdx.y;
    const int n = nh >> 3, h = nh & 7;
    const int s0 = blockIdx.x * 64;
    const float* cp = ctx + (size_t)nh * 4096;
    const size_t qrs = (size_t)NN * SP;
    const float* Qp = Qbuf + (size_t)(h * 64) * qrs + (size_t)n * SP;
    float* op = out + (size_t)nh * 64 * SP;
    __shared__ float Cs[64][65];
    __shared__ float Bs[64][68];
    const int tx = threadIdx.x, ty = threadIdx.y;
    const int tid = ty * 16 + tx;
#pragma unroll
    for (int i = 0; i < 4; ++i) {
        int q = tid + i * 256;
        int k = q >> 4, v4 = (q & 15) * 4;
        float4 a = *(const float4*)&cp[k * 64 + v4];
        Cs[k][v4] = a.x; Cs[k][v4 + 1] = a.y; Cs[k][v4 + 2] = a.z; Cs[k][v4 + 3] = a.w;
        float4 b = *(const float4*)&Qp[(size_t)k * qrs + s0 + v4];
        Bs[k][v4] = b.x; Bs[k][v4 + 1] = b.y; Bs[k][v4 + 2] = b.z; Bs[k][v4 + 3] = b.w;
    }
    __syncthreads();
    float acc[4][4] = {};
    const int v0 = ty * 4, j0 = tx * 4;
#pragma unroll 8
    for (int k = 0; k < 64; ++k) {
        float a[4], b[4];
#pragma unroll
        for (int i = 0; i < 4; ++i) a[i] = Cs[k][v0 + i];
#pragma unroll
        for (int j = 0; j < 4; ++j) b[j] = Bs[k][j0 + j];
#pragma unroll
        for (int i = 0; i < 4; ++i)
#pragma unroll
            for (int j = 0; j < 4; ++j)
                acc[i][j] += a[i] * b[j];
    }
#pragma unroll
    for (int i = 0; i < 4; ++i) {
        float4 v;
        v.x = acc[i][0]; v.y = acc[i][1]; v.z = acc[i][2]; v.w = acc[i][3];
        *(float4*)&op[(size_t)(v0 + i) * SP + s0 + j0] = v;
    }
}

// ---------------- x = rep + fused ; partial sums ---------------------------
__global__ __launch_bounds__(256)
void add_stats_kernel(const float* __restrict__ rep, const float* __restrict__ rgb,
                      const float* __restrict__ flow, float* __restrict__ xout,
                      double* __restrict__ partials)
{
    const int nc = blockIdx.x;
    const int n = nc >> 9, c = nc & 511;
    const float* f = (c < 256) ? rgb + ((size_t)n * 256 + c) * SP
                               : flow + ((size_t)n * 256 + (c - 256)) * SP;
    const float* r = rep + (size_t)nc * SP;
    float* xo = xout + (size_t)nc * SP;
    double ls = 0.0, lss = 0.0;
    for (int i = threadIdx.x; i < SP; i += 256) {
        float x = r[i] + f[i];
        xo[i] = x;
        ls += (double)x;
        lss += (double)x * (double)x;
    }
    __shared__ double s1[256], s2[256];
    const int tid = threadIdx.x;
    s1[tid] = ls; s2[tid] = lss;
    __syncthreads();
    for (int s = 128; s > 0; s >>= 1) {
        if (tid < s) { s1[tid] += s1[tid + s]; s2[tid] += s2[tid + s]; }
        __syncthreads();
    }
    if (tid == 0) {
        partials[2 * nc] = s1[0];
        partials[2 * nc + 1] = s2[0];
    }
}

__global__ __launch_bounds__(256)
void stats_final_kernel(const double* __restrict__ partials, float* __restrict__ mv)
{
    double ls = 0.0, lss = 0.0;
    for (int i = threadIdx.x; i < STATS_BLOCKS; i += 256) {
        ls += partials[2 * i];
        lss += partials[2 * i + 1];
    }
    __shared__ double s1[256], s2[256];
    const int tid = threadIdx.x;
    s1[tid] = ls; s2[tid] = lss;
    __syncthreads();
    for (int s = 128; s > 0; s >>= 1) {
        if (tid < s) { s1[tid] += s1[tid + s]; s2[tid] += s2[tid + s]; }
        __syncthreads();
    }
    if (tid == 0) {
        double mean = s1[0] / TOTAL_ELEMS;
        double var = s2[0] / TOTAL_ELEMS - mean * mean;
        mv[0] = (float)mean;
        mv[1] = (float)(1.0 / sqrt(var + 1e-5));
    }
}

__global__ __launch_bounds__(256)
void normalize_kernel(float* __restrict__ x, const float* __restrict__ mv)
{
    const float mean = mv[0], inv = mv[1];
    float* p = x + (size_t)blockIdx.x * SP;
    for (int i = threadIdx.x; i < SP; i += 256)
        p[i] = (p[i] - mean) * inv;
}

// ---------------------------------------------------------------------------
extern "C" void kernel_launch(void* const* d_in, const int* in_sizes, int n_in,
                              void* d_out, int out_size, void* d_ws, size_t ws_size,
                              hipStream_t stream)
{
    (void)in_sizes; (void)n_in; (void)out_size; (void)ws_size;
    const float* rgb = (const float*)d_in[0];
    const float* flow = (const float*)d_in[1];
    float* ws = (float*)d_ws;

    float* bufK = ws;                           // [N,512,S] f32 (layout A)
    float* bufQ = ws + NB;                      // Q: [512,N,S] f32 (layout B)
    short* actT = (short*)(ws + 2 * NB);        // [N,S,256] bf16 (proj act^T)
    short* wB   = actT + (size_t)NN * SP * 256; // 7 bf16 weight mats (655360)
    float* ctxBuf = (float*)(wB + 655360);      // 32*4096 f32
    double* partials = (double*)(ctxBuf + 32 * 4096);
    float* mv = (float*)(partials + 2 * STATS_BLOCKS);
    float* ctxPart = (float*)actT;              // alias (dead after projections)
    short* dwT = (short*)(bufQ + NB / 2);       // [N,256,S] bf16, aliases Q-flow half
    short* rpDw = (short*)bufK;                 // rp dw out bf16 (bufK dead after ctx)
    short* rpActT = (short*)bufQ;               // rp act^T bf16 (bufQ dead after att)
    float* rep = bufK;                          // rp GEMM out f32 (rpDw dead)
    float* bufV = (float*)d_out;                // V / aggregated (layout A)

    const size_t nsA = (size_t)C2 * SP, csA = SP;      // layout A strides
    const size_t nsB = (size_t)SP, csB = (size_t)NN * SP; // layout B (Q)

    // ---- weight conversions (order must match proj order below) ----
    const int wIdx[7] = {2, 10, 14, 22, 6, 18, 26};    // Krgb,Vrgb,Kflow,Vflow,Qrgb,Qflow,rp
    for (int p = 0; p < 6; ++p)
        cvt_kernel<<<64, 256, 0, stream>>>((const float*)d_in[wIdx[p] + 2],
                                           wB + (size_t)p * 65536, 65536);
    cvt_kernel<<<256, 256, 0, stream>>>((const float*)d_in[28], wB + 6 * 65536, 262144);

    // ---- projections: order K-rgb, V-rgb, K-flow, V-flow, Q-rgb, Q-flow ----
    const float* src[6] = {rgb, rgb, flow, flow, rgb, flow};
    float* dst[6] = {bufK, bufV, bufK, bufV, bufQ, bufQ};
    const int choff[6] = {0, 0, 256, 256, 0, 256};
    for (int p = 0; p < 6; ++p) {
        const int wi = wIdx[p];
        const bool layB = (p >= 4);
        dw_conv_kernel<<<dim3(TT, C1, NN), 256, 0, stream>>>(
            src[p], (const float*)d_in[wi], (const float*)d_in[wi + 1], dwT, C1);
        transpose_kernel<<<dim3(SP / 64, C1 / 64, NN), 256, 0, stream>>>(dwT, actT, C1);
        pw_mfma_kernel<<<dim3(SP / 128, C1 / 128, NN), 256, 0, stream>>>(
            wB + (size_t)p * 65536, (const float*)d_in[wi + 3], actT, dst[p],
            C1, layB ? nsB : nsA, layB ? csB : csA, choff[p]);
    }

    softmax_rows_kernel<<<NN * C2, 256, 0, stream>>>(bufK);
    softmax_q_kernel<<<dim3(SP / 256, NN * HEADS), 256, 0, stream>>>(bufQ);

    ctx_partial_kernel<<<dim3(CTX_CHUNKS, NN * HEADS), 256, 0, stream>>>(bufK, bufV, ctxPart);
    ctx_reduce_kernel<<<NN * HEADS, 256, 0, stream>>>(ctxPart, ctxBuf);
    att_kernel<<<dim3(SP / 64, NN * HEADS), dim3(16, 16), 0, stream>>>(ctxBuf, bufQ, bufV);

    // ---- reprojection: dw(512) -> transpose -> MFMA GEMM 512x512 ----
    dw_conv_kernel<<<dim3(TT, C2, NN), 256, 0, stream>>>(
        bufV, (const float*)d_in[26], (const float*)d_in[27], rpDw, C2);
    transpose_kernel<<<dim3(SP / 64, C2 / 64, NN), 256, 0, stream>>>(rpDw, rpActT, C2);
    pw_mfma_kernel<<<dim3(SP / 128, C2 / 128, NN), 256, 0, stream>>>(
        wB + 6 * 65536, (const float*)d_in[29], rpActT, rep, C2, nsA, csA, 0);

    // ---- residual + whole-tensor LN ----
    add_stats_kernel<<<STATS_BLOCKS, 256, 0, stream>>>(rep, rgb, flow, (float*)d_out, partials);
    stats_final_kernel<<<1, 256, 0, stream>>>(partials, mv);
    normalize_kernel<<<STATS_BLOCKS, 256, 0, stream>>>((float*)d_out, mv);
}

// Round 3
// 1072.320 us; speedup vs baseline: 1.8070x; 1.1522x over previous
//
#include <hip/hip_runtime.h>
#include <math.h>

// ---------------------------------------------------------------------------
// EfficientAttention (dual-stream) — round 3: sliding-window depthwise conv.
//   dw conv: block per (n,c,t-half), 2-slice LDS ring, each input slice
//   loaded once; 9 LDS reads feed 3 register accumulators (t-1,t,t+1 planes).
//   Rest unchanged from round 2 (MFMA pointwise GEMMs, fp32 attention, LN).
// ---------------------------------------------------------------------------

constexpr int NN = 4;
constexpr int C1 = 256;
constexpr int C2 = 512;
constexpr int TT = 16;
constexpr int HHD = 28;
constexpr int WWD = 28;
constexpr int SP = TT * HHD * WWD;                // 12544
constexpr long long NB = (long long)NN * C2 * SP; // 25,690,112 floats
constexpr int HEADS = 8;
constexpr int CTX_CHUNKS = 49;                    // SP / 256
constexpr int STATS_BLOCKS = NN * C2;             // 2048
constexpr double TOTAL_ELEMS = (double)NB;

typedef __attribute__((ext_vector_type(8))) short bf16x8;
typedef __attribute__((ext_vector_type(4))) float f32x4;

__device__ __forceinline__ short f2bf(float f)
{
    unsigned u = __float_as_uint(f);
    unsigned r = u + 0x7FFFu + ((u >> 16) & 1u);
    return (short)(r >> 16);
}

__device__ __forceinline__ void gload16(const short* g, short* l)
{
    __builtin_amdgcn_global_load_lds(
        (const __attribute__((address_space(1))) unsigned int*)g,
        (__attribute__((address_space(3))) unsigned int*)l,
        16, 0, 0);
}

// ---------------- fp32 -> bf16 weight conversion ---------------------------
__global__ __launch_bounds__(256)
void cvt_kernel(const float* __restrict__ in, short* __restrict__ out, int n)
{
    int i = blockIdx.x * 1024 + threadIdx.x;
#pragma unroll
    for (int k = 0; k < 4; ++k, i += 256)
        if (i < n) out[i] = f2bf(in[i]);
}

// ---------------- depthwise 3x3x3 conv + bias -> bf16 (sliding-t) ----------
// grid: (2, Cin, NN), block 256. in: [N,Cin,T,784] fp32; out: same, bf16.
// Block handles out t in [t0,t0+8). 2-slice LDS ring; each slice loaded once;
// 9 LDS reads per position feed 3 accumulators (planes W[2],W[1],W[0]).
__global__ __launch_bounds__(256)
void dw_conv_kernel(const float* __restrict__ in, const float* __restrict__ wgt,
                    const float* __restrict__ bias, short* __restrict__ out, int Cin)
{
    const int split = blockIdx.x;
    const int c = blockIdx.y, n = blockIdx.z;
    const int t0 = split * 8, t1 = t0 + 8;
    const int zs = (t0 - 1 > 0) ? t0 - 1 : 0;
    const int ze = (t1 < 15) ? t1 : 15;
    __shared__ float tile[2][900];
    const float* inp = in + ((size_t)(n * Cin + c)) * TT * 784;
    short* op = out + ((size_t)(n * Cin + c)) * TT * 784;
    float wr[27];
#pragma unroll
    for (int i = 0; i < 27; ++i) wr[i] = wgt[c * 27 + i];
    const float bv = bias[c];
    const int tid = threadIdx.x;

    int hw[4];
#pragma unroll
    for (int p = 0; p < 4; ++p) {
        int idx = tid + p * 256;
        int hh = idx / 28, ww = idx - hh * 28;
        hw[p] = hh * 30 + ww;            // top-left of 3x3 window in padded slice
    }
    float a0[4], a1[4], a2[4];
#pragma unroll
    for (int p = 0; p < 4; ++p) { a0[p] = bv; a1[p] = bv; a2[p] = bv; }

    for (int z = zs; z <= ze; ++z) {
        float* tb = tile[z & 1];
        const float* gsrc = inp + (size_t)z * 784;
        for (int i = tid; i < 900; i += 256) {
            int y = i / 30, x = i - y * 30;
            float v = 0.f;
            if (y >= 1 && y <= 28 && x >= 1 && x <= 28)
                v = gsrc[(y - 1) * 28 + (x - 1)];
            tb[i] = v;
        }
        __syncthreads();
#pragma unroll
        for (int p = 0; p < 4; ++p) {
            const bool act = (p < 3) || (tid < 16);
            if (!act) continue;
            float v[9];
#pragma unroll
            for (int dh = 0; dh < 3; ++dh)
#pragma unroll
                for (int dw = 0; dw < 3; ++dw)
                    v[dh * 3 + dw] = tb[hw[p] + dh * 30 + dw];
#pragma unroll
            for (int i = 0; i < 9; ++i) {
                a0[p] += v[i] * wr[18 + i];
                a1[p] += v[i] * wr[9 + i];
                a2[p] += v[i] * wr[i];
            }
        }
        if (z - 1 >= t0 && z - 1 < t1) {
#pragma unroll
            for (int p = 0; p < 4; ++p)
                if ((p < 3) || (tid < 16))
                    op[(size_t)(z - 1) * 784 + tid + p * 256] = f2bf(a0[p]);
        }
#pragma unroll
        for (int p = 0; p < 4; ++p) { a0[p] = a1[p]; a1[p] = a2[p]; a2[p] = bv; }
        // no second sync needed: next load writes the other ring buffer; the
        // same-buffer reuse (z+2) is separated by the next iteration's sync.
    }
    if (ze >= t0 && ze < t1) {   // final output t=ze (only split 1, ze=15)
#pragma unroll
        for (int p = 0; p < 4; ++p)
            if ((p < 3) || (tid < 16))
                op[(size_t)ze * 784 + tid + p * 256] = f2bf(a0[p]);
    }
}

// ---------------- bf16 transpose [C][S] -> [S][C] --------------------------
// grid: (SP/64, C/64, NN), block 256.
__global__ __launch_bounds__(256)
void transpose_kernel(const short* __restrict__ in, short* __restrict__ outT, int C)
{
    __shared__ short t[64][72];
    const int s0 = blockIdx.x * 64, c0 = blockIdx.y * 64, n = blockIdx.z;
    const short* ip = in + ((size_t)n * C + c0) * SP + s0;
    short* op = outT + ((size_t)n * SP + s0) * C + c0;
    const int tid = threadIdx.x;
    const int r = tid >> 3, q = (tid & 7) << 3;
#pragma unroll
    for (int p = 0; p < 2; ++p) {
        int c = r + p * 32;
        *(bf16x8*)&t[c][q] = *(const bf16x8*)(ip + (size_t)c * SP + q);
    }
    __syncthreads();
#pragma unroll
    for (int p = 0; p < 2; ++p) {
        int s = r + p * 32;
        bf16x8 v;
#pragma unroll
        for (int j = 0; j < 8; ++j) v[j] = t[q + j][s];
        *(bf16x8*)(op + (size_t)s * C + q) = v;
    }
}

// ---------------- pointwise conv: bf16 MFMA GEMM ---------------------------
// D[m][s] = sum_k W[m][k]*actT[s][k] + bias[m]
// grid: (SP/128, Cout/128, NN), block 256 (4 waves, each 64x64 output).
__global__ __launch_bounds__(256)
void pw_mfma_kernel(const short* __restrict__ Wb, const float* __restrict__ bias,
                    const short* __restrict__ actT, float* __restrict__ out,
                    int Cin, size_t nStride, size_t cStride, int chOff)
{
    __shared__ short lA[128 * 64];
    __shared__ short lB[128 * 64];
    const int tid = threadIdx.x;
    const int w = tid >> 6, lane = tid & 63;
    const int s0 = blockIdx.x * 128;
    const int m0 = blockIdx.y * 128;
    const int n = blockIdx.z;
    const short* aSrc = Wb + (size_t)m0 * Cin;
    const short* bSrc = actT + ((size_t)n * SP + s0) * Cin;
    f32x4 acc[4][4];
#pragma unroll
    for (int i = 0; i < 4; ++i)
#pragma unroll
        for (int j = 0; j < 4; ++j)
            acc[i][j] = (f32x4){0.f, 0.f, 0.f, 0.f};
    const int lrow = lane >> 3, lslot = lane & 7;
    const int wr = w >> 1, wc = w & 1;

    for (int kt = 0; kt < Cin; kt += 64) {
#pragma unroll
        for (int c = 0; c < 4; ++c) {
            const int chunk = w * 4 + c;
            const int row = chunk * 8 + lrow;
            const int ss = lslot ^ (row & 7);
            gload16(aSrc + (size_t)row * Cin + kt + ss * 8, &lA[chunk * 512]);
            gload16(bSrc + (size_t)row * Cin + kt + ss * 8, &lB[chunk * 512]);
        }
        __syncthreads();
#pragma unroll
        for (int kf = 0; kf < 2; ++kf) {
            bf16x8 af[4], bfr[4];
            const int kb = kf * 4 + (lane >> 4);
#pragma unroll
            for (int i = 0; i < 4; ++i) {
                const int row = wr * 64 + i * 16 + (lane & 15);
                af[i] = *(const bf16x8*)&lA[row * 64 + ((kb ^ (row & 7)) << 3)];
            }
#pragma unroll
            for (int j = 0; j < 4; ++j) {
                const int row = wc * 64 + j * 16 + (lane & 15);
                bfr[j] = *(const bf16x8*)&lB[row * 64 + ((kb ^ (row & 7)) << 3)];
            }
#pragma unroll
            for (int i = 0; i < 4; ++i)
#pragma unroll
                for (int j = 0; j < 4; ++j)
                    acc[i][j] = __builtin_amdgcn_mfma_f32_16x16x32_bf16(
                        af[i], bfr[j], acc[i][j], 0, 0, 0);
        }
        __syncthreads();
    }

    float* op = out + (size_t)n * nStride + (size_t)chOff * cStride;
#pragma unroll
    for (int i = 0; i < 4; ++i) {
        const int mBase = m0 + wr * 64 + i * 16 + (lane >> 4) * 4;
#pragma unroll
        for (int j = 0; j < 4; ++j) {
            const int s = s0 + wc * 64 + j * 16 + (lane & 15);
#pragma unroll
            for (int r = 0; r < 4; ++r) {
                const int m = mBase + r;
                op[(size_t)m * cStride + s] = acc[i][j][r] + bias[m];
            }
        }
    }
}

// ---------------- softmax over S (rows of [*, S]) --------------------------
__global__ __launch_bounds__(256)
void softmax_rows_kernel(float* __restrict__ data)
{
    float* p = data + (size_t)blockIdx.x * SP;
    __shared__ float sm[4];
    __shared__ float bc;
    const int tid = threadIdx.x, wv = tid >> 6, ln = tid & 63;
    float m = -1e30f;
    for (int i = tid; i < SP; i += 256) m = fmaxf(m, p[i]);
    for (int o = 32; o; o >>= 1) m = fmaxf(m, __shfl_down(m, o, 64));
    if (ln == 0) sm[wv] = m;
    __syncthreads();
    if (tid == 0) bc = fmaxf(fmaxf(sm[0], sm[1]), fmaxf(sm[2], sm[3]));
    __syncthreads();
    m = bc;
    float sum = 0.f;
    for (int i = tid; i < SP; i += 256) { float e = __expf(p[i] - m); p[i] = e; sum += e; }
    for (int o = 32; o; o >>= 1) sum += __shfl_down(sum, o, 64);
    __syncthreads();
    if (ln == 0) sm[wv] = sum;
    __syncthreads();
    if (tid == 0) bc = sm[0] + sm[1] + sm[2] + sm[3];
    __syncthreads();
    const float inv = 1.f / bc;
    for (int i = tid; i < SP; i += 256) p[i] *= inv;
}

// ---------------- softmax over 64 head-channels (Q, layout [c][n][s]) ------
__global__ __launch_bounds__(256)
void softmax_q_kernel(float* __restrict__ data)
{
    const int s = blockIdx.x * 256 + threadIdx.x;
    const int nh = blockIdx.y;
    const int n = nh >> 3, h = nh & 7;
    const size_t cs = (size_t)NN * SP;
    float* p = data + (size_t)(h * 64) * cs + (size_t)n * SP + s;
    float v[64];
    float m = -1e30f;
#pragma unroll
    for (int c = 0; c < 64; ++c) { v[c] = p[c * cs]; m = fmaxf(m, v[c]); }
    float sum = 0.f;
#pragma unroll
    for (int c = 0; c < 64; ++c) { v[c] = __expf(v[c] - m); sum += v[c]; }
    const float inv = 1.f / sum;
#pragma unroll
    for (int c = 0; c < 64; ++c) p[c * cs] = v[c] * inv;
}

// ---------------- ctx = K . V^T (chunked partials) -------------------------
__global__ __launch_bounds__(256)
void ctx_partial_kernel(const float* __restrict__ Kbuf, const float* __restrict__ Vbuf,
                        float* __restrict__ part)
{
    const int chunk = blockIdx.x, nh = blockIdx.y;
    const int sBeg = chunk * 256;
    const float* Kp = Kbuf + (size_t)nh * 64 * SP;
    const float* Vp = Vbuf + (size_t)nh * 64 * SP;
    __shared__ float Ks[64][33], Vs[64][33];
    const int tid = threadIdx.x;
    const int kk = (tid >> 4) * 4, vv = (tid & 15) * 4;
    float acc[4][4] = {};
    for (int st = 0; st < 256; st += 32) {
#pragma unroll
        for (int i = 0; i < 2; ++i) {
            int l = tid + i * 256;
            int r = l >> 3, cq = (l & 7) * 4;
            float4 a = *(const float4*)&Kp[(size_t)r * SP + sBeg + st + cq];
            Ks[r][cq] = a.x; Ks[r][cq + 1] = a.y; Ks[r][cq + 2] = a.z; Ks[r][cq + 3] = a.w;
            float4 b = *(const float4*)&Vp[(size_t)r * SP + sBeg + st + cq];
            Vs[r][cq] = b.x; Vs[r][cq + 1] = b.y; Vs[r][cq + 2] = b.z; Vs[r][cq + 3] = b.w;
        }
        __syncthreads();
#pragma unroll 8
        for (int s = 0; s < 32; ++s) {
            float a[4], b[4];
#pragma unroll
            for (int i = 0; i < 4; ++i) a[i] = Ks[kk + i][s];
#pragma unroll
            for (int j = 0; j < 4; ++j) b[j] = Vs[vv + j][s];
#pragma unroll
            for (int i = 0; i < 4; ++i)
#pragma unroll
                for (int j = 0; j < 4; ++j)
                    acc[i][j] += a[i] * b[j];
        }
        __syncthreads();
    }
    float* op = part + ((size_t)nh * CTX_CHUNKS + chunk) * 4096;
#pragma unroll
    for (int i = 0; i < 4; ++i)
#pragma unroll
        for (int j = 0; j < 4; ++j)
            op[(kk + i) * 64 + vv + j] = acc[i][j];
}

__global__ __launch_bounds__(256)
void ctx_reduce_kernel(const float* __restrict__ part, float* __restrict__ ctx)
{
    const int nh = blockIdx.x;
    for (int e = threadIdx.x; e < 4096; e += 256) {
        float s = 0.f;
        for (int c = 0; c < CTX_CHUNKS; ++c)
            s += part[((size_t)nh * CTX_CHUNKS + c) * 4096 + e];
        ctx[(size_t)nh * 4096 + e] = s;
    }
}

// ---------------- att[v,s] = sum_k ctx[k,v] * Q[k,s] (Q layout [c][n][s]) --
__global__ __launch_bounds__(256)
void att_kernel(const float* __restrict__ ctx, const float* __restrict__ Qbuf,
                float* __restrict__ out)
{
    const int nh = blockIdx.y;
    const int n = nh >> 3, h = nh & 7;
    const int s0 = blockIdx.x * 64;
    const float* cp = ctx + (size_t)nh * 4096;
    const size_t qrs = (size_t)NN * SP;
    const float* Qp = Qbuf + (size_t)(h * 64) * qrs + (size_t)n * SP;
    float* op = out + (size_t)nh * 64 * SP;
    __shared__ float Cs[64][65];
    __shared__ float Bs[64][68];
    const int tx = threadIdx.x, ty = threadIdx.y;
    const int tid = ty * 16 + tx;
#pragma unroll
    for (int i = 0; i < 4; ++i) {
        int q = tid + i * 256;
        int k = q >> 4, v4 = (q & 15) * 4;
        float4 a = *(const float4*)&cp[k * 64 + v4];
        Cs[k][v4] = a.x; Cs[k][v4 + 1] = a.y; Cs[k][v4 + 2] = a.z; Cs[k][v4 + 3] = a.w;
        float4 b = *(const float4*)&Qp[(size_t)k * qrs + s0 + v4];
        Bs[k][v4] = b.x; Bs[k][v4 + 1] = b.y; Bs[k][v4 + 2] = b.z; Bs[k][v4 + 3] = b.w;
    }
    __syncthreads();
    float acc[4][4] = {};
    const int v0 = ty * 4, j0 = tx * 4;
#pragma unroll 8
    for (int k = 0; k < 64; ++k) {
        float a[4], b[4];
#pragma unroll
        for (int i = 0; i < 4; ++i) a[i] = Cs[k][v0 + i];
#pragma unroll
        for (int j = 0; j < 4; ++j) b[j] = Bs[k][j0 + j];
#pragma unroll
        for (int i = 0; i < 4; ++i)
#pragma unroll
            for (int j = 0; j < 4; ++j)
                acc[i][j] += a[i] * b[j];
    }
#pragma unroll
    for (int i = 0; i < 4; ++i) {
        float4 v;
        v.x = acc[i][0]; v.y = acc[i][1]; v.z = acc[i][2]; v.w = acc[i][3];
        *(float4*)&op[(size_t)(v0 + i) * SP + s0 + j0] = v;
    }
}

// ---------------- x = rep + fused ; partial sums ---------------------------
__global__ __launch_bounds__(256)
void add_stats_kernel(const float* __restrict__ rep, const float* __restrict__ rgb,
                      const float* __restrict__ flow, float* __restrict__ xout,
                      double* __restrict__ partials)
{
    const int nc = blockIdx.x;
    const int n = nc >> 9, c = nc & 511;
    const float* f = (c < 256) ? rgb + ((size_t)n * 256 + c) * SP
                               : flow + ((size_t)n * 256 + (c - 256)) * SP;
    const float* r = rep + (size_t)nc * SP;
    float* xo = xout + (size_t)nc * SP;
    double ls = 0.0, lss = 0.0;
    for (int i = threadIdx.x; i < SP; i += 256) {
        float x = r[i] + f[i];
        xo[i] = x;
        ls += (double)x;
        lss += (double)x * (double)x;
    }
    __shared__ double s1[256], s2[256];
    const int tid = threadIdx.x;
    s1[tid] = ls; s2[tid] = lss;
    __syncthreads();
    for (int s = 128; s > 0; s >>= 1) {
        if (tid < s) { s1[tid] += s1[tid + s]; s2[tid] += s2[tid + s]; }
        __syncthreads();
    }
    if (tid == 0) {
        partials[2 * nc] = s1[0];
        partials[2 * nc + 1] = s2[0];
    }
}

__global__ __launch_bounds__(256)
void stats_final_kernel(const double* __restrict__ partials, float* __restrict__ mv)
{
    double ls = 0.0, lss = 0.0;
    for (int i = threadIdx.x; i < STATS_BLOCKS; i += 256) {
        ls += partials[2 * i];
        lss += partials[2 * i + 1];
    }
    __shared__ double s1[256], s2[256];
    const int tid = threadIdx.x;
    s1[tid] = ls; s2[tid] = lss;
    __syncthreads();
    for (int s = 128; s > 0; s >>= 1) {
        if (tid < s) { s1[tid] += s1[tid + s]; s2[tid] += s2[tid + s]; }
        __syncthreads();
    }
    if (tid == 0) {
        double mean = s1[0] / TOTAL_ELEMS;
        double var = s2[0] / TOTAL_ELEMS - mean * mean;
        mv[0] = (float)mean;
        mv[1] = (float)(1.0 / sqrt(var + 1e-5));
    }
}

__global__ __launch_bounds__(256)
void normalize_kernel(float* __restrict__ x, const float* __restrict__ mv)
{
    const float mean = mv[0], inv = mv[1];
    float* p = x + (size_t)blockIdx.x * SP;
    for (int i = threadIdx.x; i < SP; i += 256)
        p[i] = (p[i] - mean) * inv;
}

// ---------------------------------------------------------------------------
extern "C" void kernel_launch(void* const* d_in, const int* in_sizes, int n_in,
                              void* d_out, int out_size, void* d_ws, size_t ws_size,
                              hipStream_t stream)
{
    (void)in_sizes; (void)n_in; (void)out_size; (void)ws_size;
    const float* rgb = (const float*)d_in[0];
    const float* flow = (const float*)d_in[1];
    float* ws = (float*)d_ws;

    float* bufK = ws;                           // [N,512,S] f32 (layout A)
    float* bufQ = ws + NB;                      // Q: [512,N,S] f32 (layout B)
    short* actT = (short*)(ws + 2 * NB);        // [N,S,256] bf16 (proj act^T)
    short* wB   = actT + (size_t)NN * SP * 256; // 7 bf16 weight mats (655360)
    float* ctxBuf = (float*)(wB + 655360);      // 32*4096 f32
    double* partials = (double*)(ctxBuf + 32 * 4096);
    float* mv = (float*)(partials + 2 * STATS_BLOCKS);
    float* ctxPart = (float*)actT;              // alias (dead after projections)
    short* dwT = (short*)(bufQ + NB / 2);       // [N,256,S] bf16, aliases Q-flow half
    short* rpDw = (short*)bufK;                 // rp dw out bf16 (bufK dead after ctx)
    short* rpActT = (short*)bufQ;               // rp act^T bf16 (bufQ dead after att)
    float* rep = bufK;                          // rp GEMM out f32 (rpDw dead)
    float* bufV = (float*)d_out;                // V / aggregated (layout A)

    const size_t nsA = (size_t)C2 * SP, csA = SP;          // layout A strides
    const size_t nsB = (size_t)SP, csB = (size_t)NN * SP;  // layout B (Q)

    // ---- weight conversions (order must match proj order below) ----
    const int wIdx[7] = {2, 10, 14, 22, 6, 18, 26};    // Krgb,Vrgb,Kflow,Vflow,Qrgb,Qflow,rp
    for (int p = 0; p < 6; ++p)
        cvt_kernel<<<64, 256, 0, stream>>>((const float*)d_in[wIdx[p] + 2],
                                           wB + (size_t)p * 65536, 65536);
    cvt_kernel<<<256, 256, 0, stream>>>((const float*)d_in[28], wB + 6 * 65536, 262144);

    // ---- projections: order K-rgb, V-rgb, K-flow, V-flow, Q-rgb, Q-flow ----
    const float* src[6] = {rgb, rgb, flow, flow, rgb, flow};
    float* dst[6] = {bufK, bufV, bufK, bufV, bufQ, bufQ};
    const int choff[6] = {0, 0, 256, 256, 0, 256};
    for (int p = 0; p < 6; ++p) {
        const int wi = wIdx[p];
        const bool layB = (p >= 4);
        dw_conv_kernel<<<dim3(2, C1, NN), 256, 0, stream>>>(
            src[p], (const float*)d_in[wi], (const float*)d_in[wi + 1], dwT, C1);
        transpose_kernel<<<dim3(SP / 64, C1 / 64, NN), 256, 0, stream>>>(dwT, actT, C1);
        pw_mfma_kernel<<<dim3(SP / 128, C1 / 128, NN), 256, 0, stream>>>(
            wB + (size_t)p * 65536, (const float*)d_in[wi + 3], actT, dst[p],
            C1, layB ? nsB : nsA, layB ? csB : csA, choff[p]);
    }

    softmax_rows_kernel<<<NN * C2, 256, 0, stream>>>(bufK);
    softmax_q_kernel<<<dim3(SP / 256, NN * HEADS), 256, 0, stream>>>(bufQ);

    ctx_partial_kernel<<<dim3(CTX_CHUNKS, NN * HEADS), 256, 0, stream>>>(bufK, bufV, ctxPart);
    ctx_reduce_kernel<<<NN * HEADS, 256, 0, stream>>>(ctxPart, ctxBuf);
    att_kernel<<<dim3(SP / 64, NN * HEADS), dim3(16, 16), 0, stream>>>(ctxBuf, bufQ, bufV);

    // ---- reprojection: dw(512) -> transpose -> MFMA GEMM 512x512 ----
    dw_conv_kernel<<<dim3(2, C2, NN), 256, 0, stream>>>(
        bufV, (const float*)d_in[26], (const float*)d_in[27], rpDw, C2);
    transpose_kernel<<<dim3(SP / 64, C2 / 64, NN), 256, 0, stream>>>(rpDw, rpActT, C2);
    pw_mfma_kernel<<<dim3(SP / 128, C2 / 128, NN), 256, 0, stream>>>(
        wB + 6 * 65536, (const float*)d_in[29], rpActT, rep, C2, nsA, csA, 0);

    // ---- residual + whole-tensor LN ----
    add_stats_kernel<<<STATS_BLOCKS, 256, 0, stream>>>(rep, rgb, flow, (float*)d_out, partials);
    stats_final_kernel<<<1, 256, 0, stream>>>(partials, mv);
    normalize_kernel<<<STATS_BLOCKS, 256, 0, stream>>>((float*)d_out, mv);
}

// Round 4
// 871.862 us; speedup vs baseline: 2.2225x; 1.2299x over previous
//
#include <hip/hip_runtime.h>
#include <math.h>

// ---------------------------------------------------------------------------
// EfficientAttention (dual-stream) — round 4: traffic reduction.
//   * K/Q/V/aggregated all bf16 (pw GEMM writes bf16; consumers convert).
//   * softmax_K fused: row_stats (max, 1/sum-exp) + exp on-the-fly in ctx.
//   * softmax_Q fused into att_kernel (column softmax in LDS, inv in epilogue).
//   * residual + LN stats fused into rp GEMM epilogue (no rep buffer).
// ---------------------------------------------------------------------------

constexpr int NN = 4;
constexpr int C1 = 256;
constexpr int C2 = 512;
constexpr int TT = 16;
constexpr int HHD = 28;
constexpr int WWD = 28;
constexpr int SP = TT * HHD * WWD;                // 12544
constexpr long long NB = (long long)NN * C2 * SP; // 25,690,112
constexpr int HEADS = 8;
constexpr int CTX_CHUNKS = 49;                    // SP / 256
constexpr int STATS_PARTS = 98 * 4 * 4;           // rp GEMM grid = 1568
constexpr double TOTAL_ELEMS = (double)NB;

typedef __attribute__((ext_vector_type(8))) short bf16x8;
typedef __attribute__((ext_vector_type(4))) short bf16x4;
typedef __attribute__((ext_vector_type(4))) float f32x4;

__device__ __forceinline__ short f2bf(float f)
{
    unsigned u = __float_as_uint(f);
    unsigned r = u + 0x7FFFu + ((u >> 16) & 1u);
    return (short)(r >> 16);
}
__device__ __forceinline__ float bf2f(short s)
{
    return __uint_as_float(((unsigned)(unsigned short)s) << 16);
}
__device__ __forceinline__ float toF(float x) { return x; }
__device__ __forceinline__ float toF(short x) { return bf2f(x); }

__device__ __forceinline__ void gload16(const short* g, short* l)
{
    __builtin_amdgcn_global_load_lds(
        (const __attribute__((address_space(1))) unsigned int*)g,
        (__attribute__((address_space(3))) unsigned int*)l,
        16, 0, 0);
}

// ---------------- fp32 -> bf16 weight conversion ---------------------------
__global__ __launch_bounds__(256)
void cvt_kernel(const float* __restrict__ in, short* __restrict__ out, int n)
{
    int i = blockIdx.x * 1024 + threadIdx.x;
#pragma unroll
    for (int k = 0; k < 4; ++k, i += 256)
        if (i < n) out[i] = f2bf(in[i]);
}

// ---------------- depthwise 3x3x3 conv + bias -> bf16 (sliding-t) ----------
// grid: (2, Cin, NN), block 256. in: [N,Cin,T,784] (f32 or bf16); out bf16.
template<typename IT>
__global__ __launch_bounds__(256)
void dw_conv_kernel(const IT* __restrict__ in, const float* __restrict__ wgt,
                    const float* __restrict__ bias, short* __restrict__ out, int Cin)
{
    const int split = blockIdx.x;
    const int c = blockIdx.y, n = blockIdx.z;
    const int t0 = split * 8, t1 = t0 + 8;
    const int zs = (t0 - 1 > 0) ? t0 - 1 : 0;
    const int ze = (t1 < 15) ? t1 : 15;
    __shared__ float tile[2][900];
    const IT* inp = in + ((size_t)(n * Cin + c)) * TT * 784;
    short* op = out + ((size_t)(n * Cin + c)) * TT * 784;
    float wr[27];
#pragma unroll
    for (int i = 0; i < 27; ++i) wr[i] = wgt[c * 27 + i];
    const float bv = bias[c];
    const int tid = threadIdx.x;

    int hw[4];
#pragma unroll
    for (int p = 0; p < 4; ++p) {
        int idx = tid + p * 256;
        int hh = idx / 28, ww = idx - hh * 28;
        hw[p] = hh * 30 + ww;
    }
    float a0[4], a1[4], a2[4];
#pragma unroll
    for (int p = 0; p < 4; ++p) { a0[p] = bv; a1[p] = bv; a2[p] = bv; }

    for (int z = zs; z <= ze; ++z) {
        float* tb = tile[z & 1];
        const IT* gsrc = inp + (size_t)z * 784;
        for (int i = tid; i < 900; i += 256) {
            int y = i / 30, x = i - y * 30;
            float v = 0.f;
            if (y >= 1 && y <= 28 && x >= 1 && x <= 28)
                v = toF(gsrc[(y - 1) * 28 + (x - 1)]);
            tb[i] = v;
        }
        __syncthreads();
#pragma unroll
        for (int p = 0; p < 4; ++p) {
            const bool act = (p < 3) || (tid < 16);
            if (!act) continue;
            float v[9];
#pragma unroll
            for (int dh = 0; dh < 3; ++dh)
#pragma unroll
                for (int dw = 0; dw < 3; ++dw)
                    v[dh * 3 + dw] = tb[hw[p] + dh * 30 + dw];
#pragma unroll
            for (int i = 0; i < 9; ++i) {
                a0[p] += v[i] * wr[18 + i];
                a1[p] += v[i] * wr[9 + i];
                a2[p] += v[i] * wr[i];
            }
        }
        if (z - 1 >= t0 && z - 1 < t1) {
#pragma unroll
            for (int p = 0; p < 4; ++p)
                if ((p < 3) || (tid < 16))
                    op[(size_t)(z - 1) * 784 + tid + p * 256] = f2bf(a0[p]);
        }
#pragma unroll
        for (int p = 0; p < 4; ++p) { a0[p] = a1[p]; a1[p] = a2[p]; a2[p] = bv; }
    }
    if (ze >= t0 && ze < t1) {
#pragma unroll
        for (int p = 0; p < 4; ++p)
            if ((p < 3) || (tid < 16))
                op[(size_t)ze * 784 + tid + p * 256] = f2bf(a0[p]);
    }
}

// ---------------- bf16 transpose [C][S] -> [S][C] --------------------------
__global__ __launch_bounds__(256)
void transpose_kernel(const short* __restrict__ in, short* __restrict__ outT, int C)
{
    __shared__ short t[64][72];
    const int s0 = blockIdx.x * 64, c0 = blockIdx.y * 64, n = blockIdx.z;
    const short* ip = in + ((size_t)n * C + c0) * SP + s0;
    short* op = outT + ((size_t)n * SP + s0) * C + c0;
    const int tid = threadIdx.x;
    const int r = tid >> 3, q = (tid & 7) << 3;
#pragma unroll
    for (int p = 0; p < 2; ++p) {
        int c = r + p * 32;
        *(bf16x8*)&t[c][q] = *(const bf16x8*)(ip + (size_t)c * SP + q);
    }
    __syncthreads();
#pragma unroll
    for (int p = 0; p < 2; ++p) {
        int s = r + p * 32;
        bf16x8 v;
#pragma unroll
        for (int j = 0; j < 8; ++j) v[j] = t[q + j][s];
        *(bf16x8*)(op + (size_t)s * C + q) = v;
    }
}

// ---------------- pointwise conv: bf16 MFMA GEMM ---------------------------
// !RESID: out bf16 at outB + n*nStride + (chOff+m)*cStride + s.
// RESID:  out f32 x = acc+bias+residual to outF (layout [N,C2,S]) + LN partial
//         sums (double) per block.
template<bool RESID>
__global__ __launch_bounds__(256)
void pw_mfma_kernel(const short* __restrict__ Wb, const float* __restrict__ bias,
                    const short* __restrict__ actT, short* __restrict__ outB,
                    float* __restrict__ outF, const float* __restrict__ rgb,
                    const float* __restrict__ flow, double* __restrict__ partials,
                    int Cin, size_t nStride, size_t cStride, int chOff)
{
    __shared__ short lA[128 * 64];
    __shared__ short lB[128 * 64];
    const int tid = threadIdx.x;
    const int w = tid >> 6, lane = tid & 63;
    const int s0 = blockIdx.x * 128;
    const int m0 = blockIdx.y * 128;
    const int n = blockIdx.z;
    const short* aSrc = Wb + (size_t)m0 * Cin;
    const short* bSrc = actT + ((size_t)n * SP + s0) * Cin;
    f32x4 acc[4][4];
#pragma unroll
    for (int i = 0; i < 4; ++i)
#pragma unroll
        for (int j = 0; j < 4; ++j)
            acc[i][j] = (f32x4){0.f, 0.f, 0.f, 0.f};
    const int lrow = lane >> 3, lslot = lane & 7;
    const int wr = w >> 1, wc = w & 1;

    for (int kt = 0; kt < Cin; kt += 64) {
#pragma unroll
        for (int c = 0; c < 4; ++c) {
            const int chunk = w * 4 + c;
            const int row = chunk * 8 + lrow;
            const int ss = lslot ^ (row & 7);
            gload16(aSrc + (size_t)row * Cin + kt + ss * 8, &lA[chunk * 512]);
            gload16(bSrc + (size_t)row * Cin + kt + ss * 8, &lB[chunk * 512]);
        }
        __syncthreads();
#pragma unroll
        for (int kf = 0; kf < 2; ++kf) {
            bf16x8 af[4], bfr[4];
            const int kb = kf * 4 + (lane >> 4);
#pragma unroll
            for (int i = 0; i < 4; ++i) {
                const int row = wr * 64 + i * 16 + (lane & 15);
                af[i] = *(const bf16x8*)&lA[row * 64 + ((kb ^ (row & 7)) << 3)];
            }
#pragma unroll
            for (int j = 0; j < 4; ++j) {
                const int row = wc * 64 + j * 16 + (lane & 15);
                bfr[j] = *(const bf16x8*)&lB[row * 64 + ((kb ^ (row & 7)) << 3)];
            }
#pragma unroll
            for (int i = 0; i < 4; ++i)
#pragma unroll
                for (int j = 0; j < 4; ++j)
                    acc[i][j] = __builtin_amdgcn_mfma_f32_16x16x32_bf16(
                        af[i], bfr[j], acc[i][j], 0, 0, 0);
        }
        __syncthreads();
    }

    if constexpr (!RESID) {
        short* op = outB + (size_t)n * nStride + (size_t)chOff * cStride;
#pragma unroll
        for (int i = 0; i < 4; ++i) {
            const int mBase = m0 + wr * 64 + i * 16 + (lane >> 4) * 4;
#pragma unroll
            for (int j = 0; j < 4; ++j) {
                const int s = s0 + wc * 64 + j * 16 + (lane & 15);
#pragma unroll
                for (int r = 0; r < 4; ++r) {
                    const int m = mBase + r;
                    op[(size_t)m * cStride + s] = f2bf(acc[i][j][r] + bias[m]);
                }
            }
        }
    } else {
        float* xp = outF + (size_t)n * C2 * SP;
        const float* rbase = (m0 < 256)
            ? rgb + ((size_t)n * 256 + m0) * SP
            : flow + ((size_t)n * 256 + (m0 - 256)) * SP;
        double ls = 0.0, lss = 0.0;
#pragma unroll
        for (int i = 0; i < 4; ++i) {
            const int mBase = m0 + wr * 64 + i * 16 + (lane >> 4) * 4;
#pragma unroll
            for (int j = 0; j < 4; ++j) {
                const int s = s0 + wc * 64 + j * 16 + (lane & 15);
#pragma unroll
                for (int r = 0; r < 4; ++r) {
                    const int m = mBase + r;
                    float x = acc[i][j][r] + bias[m] +
                              rbase[(size_t)(m - m0) * SP + s];
                    xp[(size_t)m * SP + s] = x;
                    ls += (double)x;
                    lss += (double)x * (double)x;
                }
            }
        }
        __shared__ double s1[256], s2[256];
        s1[tid] = ls; s2[tid] = lss;
        __syncthreads();
        for (int st = 128; st > 0; st >>= 1) {
            if (tid < st) { s1[tid] += s1[tid + st]; s2[tid] += s2[tid + st]; }
            __syncthreads();
        }
        if (tid == 0) {
            const size_t bid = ((size_t)blockIdx.z * gridDim.y + blockIdx.y) *
                               gridDim.x + blockIdx.x;
            partials[2 * bid] = s1[0];
            partials[2 * bid + 1] = s2[0];
        }
    }
}

// ---------------- per-row (max, 1/sum exp) of K [2048 rows x S] bf16 -------
__global__ __launch_bounds__(256)
void row_stats_kernel(const short* __restrict__ K, float2* __restrict__ st)
{
    const short* p = K + (size_t)blockIdx.x * SP;
    __shared__ float sm[4];
    __shared__ float bc;
    const int tid = threadIdx.x, wv = tid >> 6, ln = tid & 63;
    float m = -1e30f;
    for (int c = tid; c < SP / 8; c += 256) {
        bf16x8 v = *(const bf16x8*)(p + c * 8);
#pragma unroll
        for (int j = 0; j < 8; ++j) m = fmaxf(m, bf2f(v[j]));
    }
    for (int o = 32; o; o >>= 1) m = fmaxf(m, __shfl_down(m, o, 64));
    if (ln == 0) sm[wv] = m;
    __syncthreads();
    if (tid == 0) bc = fmaxf(fmaxf(sm[0], sm[1]), fmaxf(sm[2], sm[3]));
    __syncthreads();
    m = bc;
    float sum = 0.f;
    for (int c = tid; c < SP / 8; c += 256) {
        bf16x8 v = *(const bf16x8*)(p + c * 8);
#pragma unroll
        for (int j = 0; j < 8; ++j) sum += __expf(bf2f(v[j]) - m);
    }
    for (int o = 32; o; o >>= 1) sum += __shfl_down(sum, o, 64);
    __syncthreads();
    if (ln == 0) sm[wv] = sum;
    __syncthreads();
    if (tid == 0) {
        float tot = sm[0] + sm[1] + sm[2] + sm[3];
        st[blockIdx.x] = (float2){m, 1.f / tot};
    }
}

// ---------------- ctx = softmax(K) . V^T (bf16 in, exp on the fly) ---------
__global__ __launch_bounds__(256)
void ctx_partial_kernel(const short* __restrict__ Kbuf, const short* __restrict__ Vbuf,
                        const float2* __restrict__ stats, float* __restrict__ part)
{
    const int chunk = blockIdx.x, nh = blockIdx.y;
    const int sBeg = chunk * 256;
    const short* Kp = Kbuf + (size_t)nh * 64 * SP;
    const short* Vp = Vbuf + (size_t)nh * 64 * SP;
    __shared__ float Ks[64][33], Vs[64][33];
    __shared__ float km[64], kinv[64];
    const int tid = threadIdx.x;
    if (tid < 64) {
        float2 s = stats[nh * 64 + tid];
        km[tid] = s.x; kinv[tid] = s.y;
    }
    __syncthreads();
    const int kk = (tid >> 4) * 4, vv = (tid & 15) * 4;
    const int lr = tid >> 2, lc = (tid & 3) * 8;
    float acc[4][4] = {};
    for (int st = 0; st < 256; st += 32) {
        bf16x8 a = *(const bf16x8*)(Kp + (size_t)lr * SP + sBeg + st + lc);
        bf16x8 b = *(const bf16x8*)(Vp + (size_t)lr * SP + sBeg + st + lc);
        const float mk = km[lr], ik = kinv[lr];
#pragma unroll
        for (int j = 0; j < 8; ++j) {
            Ks[lr][lc + j] = __expf(bf2f(a[j]) - mk) * ik;
            Vs[lr][lc + j] = bf2f(b[j]);
        }
        __syncthreads();
#pragma unroll 8
        for (int s = 0; s < 32; ++s) {
            float av[4], bv[4];
#pragma unroll
            for (int i = 0; i < 4; ++i) av[i] = Ks[kk + i][s];
#pragma unroll
            for (int j = 0; j < 4; ++j) bv[j] = Vs[vv + j][s];
#pragma unroll
            for (int i = 0; i < 4; ++i)
#pragma unroll
                for (int j = 0; j < 4; ++j)
                    acc[i][j] += av[i] * bv[j];
        }
        __syncthreads();
    }
    float* op = part + ((size_t)nh * CTX_CHUNKS + chunk) * 4096;
#pragma unroll
    for (int i = 0; i < 4; ++i)
#pragma unroll
        for (int j = 0; j < 4; ++j)
            op[(kk + i) * 64 + vv + j] = acc[i][j];
}

__global__ __launch_bounds__(256)
void ctx_reduce_kernel(const float* __restrict__ part, float* __restrict__ ctx)
{
    const int nh = blockIdx.x;
    for (int e = threadIdx.x; e < 4096; e += 256) {
        float s = 0.f;
        for (int c = 0; c < CTX_CHUNKS; ++c)
            s += part[((size_t)nh * CTX_CHUNKS + c) * 4096 + e];
        ctx[(size_t)nh * 4096 + e] = s;
    }
}

// ---------------- att[v,s] = sum_k ctx[k,v] * softmaxQ[k,s] ----------------
// Q raw bf16 layout [c][n][s]; fused column softmax; agg out bf16 [N,512,S].
__global__ __launch_bounds__(256)
void att_kernel(const float* __restrict__ ctx, const short* __restrict__ Qraw,
                short* __restrict__ out)
{
    const int nh = blockIdx.y;
    const int n = nh >> 3, h = nh & 7;
    const int s0 = blockIdx.x * 64;
    const float* cp = ctx + (size_t)nh * 4096;
    const size_t qrs = (size_t)NN * SP;
    const short* Qp = Qraw + (size_t)(h * 64) * qrs + (size_t)n * SP;
    short* op = out + (size_t)nh * 64 * SP;
    __shared__ float Cs[64][65];
    __shared__ float Bs[64][68];
    __shared__ float red[4][64];
    __shared__ float sinv[64];
    const int tx = threadIdx.x, ty = threadIdx.y;
    const int tid = ty * 16 + tx;
#pragma unroll
    for (int i = 0; i < 4; ++i) {
        int q = tid + i * 256;
        int k = q >> 4, v4 = (q & 15) * 4;
        float4 a = *(const float4*)&cp[k * 64 + v4];
        Cs[k][v4] = a.x; Cs[k][v4 + 1] = a.y; Cs[k][v4 + 2] = a.z; Cs[k][v4 + 3] = a.w;
    }
#pragma unroll
    for (int i = 0; i < 2; ++i) {
        int q = tid + i * 256;                 // 512 chunks of 8 bf16
        int k = q >> 3, g = (q & 7) * 8;
        bf16x8 b = *(const bf16x8*)(Qp + (size_t)k * qrs + s0 + g);
#pragma unroll
        for (int j = 0; j < 8; ++j) Bs[k][g + j] = bf2f(b[j]);
    }
    __syncthreads();
    // fused softmax over k per column sc
    const int sc = tid & 63, qr = tid >> 6;
    float m = -1e30f;
#pragma unroll
    for (int k = 0; k < 16; ++k) m = fmaxf(m, Bs[qr * 16 + k][sc]);
    red[qr][sc] = m;
    __syncthreads();
    m = fmaxf(fmaxf(red[0][sc], red[1][sc]), fmaxf(red[2][sc], red[3][sc]));
    __syncthreads();                           // all reads of red done
    float sum = 0.f;
#pragma unroll
    for (int k = 0; k < 16; ++k) {
        float e = __expf(Bs[qr * 16 + k][sc] - m);
        Bs[qr * 16 + k][sc] = e;
        sum += e;
    }
    red[qr][sc] = sum;
    __syncthreads();
    if (qr == 0)
        sinv[sc] = 1.f / (red[0][sc] + red[1][sc] + red[2][sc] + red[3][sc]);
    __syncthreads();

    float acc[4][4] = {};
    const int v0 = ty * 4, j0 = tx * 4;
#pragma unroll 8
    for (int k = 0; k < 64; ++k) {
        float a[4], b[4];
#pragma unroll
        for (int i = 0; i < 4; ++i) a[i] = Cs[k][v0 + i];
#pragma unroll
        for (int j = 0; j < 4; ++j) b[j] = Bs[k][j0 + j];
#pragma unroll
        for (int i = 0; i < 4; ++i)
#pragma unroll
            for (int j = 0; j < 4; ++j)
                acc[i][j] += a[i] * b[j];
    }
#pragma unroll
    for (int i = 0; i < 4; ++i) {
        bf16x4 v;
#pragma unroll
        for (int j = 0; j < 4; ++j) v[j] = f2bf(acc[i][j] * sinv[j0 + j]);
        *(bf16x4*)&op[(size_t)(v0 + i) * SP + s0 + j0] = v;
    }
}

// ---------------- LN finalize ----------------------------------------------
__global__ __launch_bounds__(256)
void stats_final_kernel(const double* __restrict__ partials, float* __restrict__ mv)
{
    double ls = 0.0, lss = 0.0;
    for (int i = threadIdx.x; i < STATS_PARTS; i += 256) {
        ls += partials[2 * i];
        lss += partials[2 * i + 1];
    }
    __shared__ double s1[256], s2[256];
    const int tid = threadIdx.x;
    s1[tid] = ls; s2[tid] = lss;
    __syncthreads();
    for (int s = 128; s > 0; s >>= 1) {
        if (tid < s) { s1[tid] += s1[tid + s]; s2[tid] += s2[tid + s]; }
        __syncthreads();
    }
    if (tid == 0) {
        double mean = s1[0] / TOTAL_ELEMS;
        double var = s2[0] / TOTAL_ELEMS - mean * mean;
        mv[0] = (float)mean;
        mv[1] = (float)(1.0 / sqrt(var + 1e-5));
    }
}

__global__ __launch_bounds__(256)
void normalize_kernel(float* __restrict__ x, const float* __restrict__ mv)
{
    const float mean = mv[0], inv = mv[1];
    float* p = x + (size_t)blockIdx.x * SP;
    for (int i = threadIdx.x; i < SP; i += 256)
        p[i] = (p[i] - mean) * inv;
}

// ---------------------------------------------------------------------------
extern "C" void kernel_launch(void* const* d_in, const int* in_sizes, int n_in,
                              void* d_out, int out_size, void* d_ws, size_t ws_size,
                              hipStream_t stream)
{
    (void)in_sizes; (void)n_in; (void)out_size; (void)ws_size;
    const float* rgb = (const float*)d_in[0];
    const float* flow = (const float*)d_in[1];
    float* ws = (float*)d_ws;

    // ws layout (float units). NB/2 floats == NB bf16.
    short* bufK = (short*)ws;                                // [N,512,S] bf16
    short* bufQ = (short*)(ws + NB / 2);                     // [512,N,S] bf16
    short* bufV = (short*)(ws + NB);                         // [N,512,S] bf16 (V, then agg)
    short* projTmpA = (short*)(ws + 3 * NB / 2);             // [N,256,S] bf16 (dw out)
    short* projTmpB = projTmpA + NB / 2;                     // [N,S,256] bf16 (act^T)
    short* wB = projTmpB + NB / 2;                           // 655360 bf16
    float2* rowStats = (float2*)(wB + 655360);               // 2048
    float* ctxBuf = (float*)(rowStats + 2048);               // 32*4096
    double* partials = (double*)(ctxBuf + 32 * 4096);        // 1568*2
    float* mv = (float*)(partials + 2 * STATS_PARTS);
    float* ctxPart = (float*)projTmpA;                       // alias: 32*49*4096 f32
    short* rpDw = bufK;                                      // rp dw out (K dead)
    short* rpActT = bufQ;                                    // rp act^T (Q dead)

    const size_t nsA = (size_t)C2 * SP, csA = SP;            // [N,512,S]
    const size_t nsB = (size_t)SP, csB = (size_t)NN * SP;    // [512,N,S]

    // ---- weight conversions ----
    const int wIdx[7] = {2, 10, 14, 22, 6, 18, 26};  // Krgb,Vrgb,Kflow,Vflow,Qrgb,Qflow,rp
    for (int p = 0; p < 6; ++p)
        cvt_kernel<<<64, 256, 0, stream>>>((const float*)d_in[wIdx[p] + 2],
                                           wB + (size_t)p * 65536, 65536);
    cvt_kernel<<<256, 256, 0, stream>>>((const float*)d_in[28], wB + 6 * 65536, 262144);

    // ---- projections ----
    const float* src[6] = {rgb, rgb, flow, flow, rgb, flow};
    short* dst[6] = {bufK, bufV, bufK, bufV, bufQ, bufQ};
    const int choff[6] = {0, 0, 256, 256, 0, 256};
    for (int p = 0; p < 6; ++p) {
        const int wi = wIdx[p];
        const bool layB = (p >= 4);
        dw_conv_kernel<float><<<dim3(2, C1, NN), 256, 0, stream>>>(
            src[p], (const float*)d_in[wi], (const float*)d_in[wi + 1], projTmpA, C1);
        transpose_kernel<<<dim3(SP / 64, C1 / 64, NN), 256, 0, stream>>>(
            projTmpA, projTmpB, C1);
        pw_mfma_kernel<false><<<dim3(SP / 128, C1 / 128, NN), 256, 0, stream>>>(
            wB + (size_t)p * 65536, (const float*)d_in[wi + 3], projTmpB, dst[p],
            nullptr, nullptr, nullptr, nullptr,
            C1, layB ? nsB : nsA, layB ? csB : csA, choff[p]);
    }

    // ---- attention ----
    row_stats_kernel<<<NN * C2, 256, 0, stream>>>(bufK, rowStats);
    ctx_partial_kernel<<<dim3(CTX_CHUNKS, NN * HEADS), 256, 0, stream>>>(
        bufK, bufV, rowStats, ctxPart);
    ctx_reduce_kernel<<<NN * HEADS, 256, 0, stream>>>(ctxPart, ctxBuf);
    att_kernel<<<dim3(SP / 64, NN * HEADS), dim3(16, 16), 0, stream>>>(
        ctxBuf, bufQ, bufV);

    // ---- reprojection (+ fused residual & LN stats) ----
    dw_conv_kernel<short><<<dim3(2, C2, NN), 256, 0, stream>>>(
        bufV, (const float*)d_in[26], (const float*)d_in[27], rpDw, C2);
    transpose_kernel<<<dim3(SP / 64, C2 / 64, NN), 256, 0, stream>>>(
        rpDw, rpActT, C2);
    pw_mfma_kernel<true><<<dim3(SP / 128, C2 / 128, NN), 256, 0, stream>>>(
        wB + 6 * 65536, (const float*)d_in[29], rpActT, nullptr,
        (float*)d_out, rgb, flow, partials, C2, 0, 0, 0);

    // ---- LN finalize ----
    stats_final_kernel<<<1, 256, 0, stream>>>(partials, mv);
    normalize_kernel<<<NN * C2, 256, 0, stream>>>((float*)d_out, mv);
}